// Round 8
// baseline (125.642 us; speedup 1.0000x reference)
//
#include <hip/hip_runtime.h>
#include <stdint.h>

typedef uint16_t u16;
typedef __attribute__((ext_vector_type(8))) short short8;
typedef __attribute__((ext_vector_type(4))) float f32x4;

#define DEV static __device__ __forceinline__

DEV u16 f2bf(float f) {
  uint32_t u = __float_as_uint(f);
  return (u16)((u + 0x7fffu + ((u >> 16) & 1u)) >> 16);
}
DEV float bf2f(u16 h) { return __uint_as_float(((uint32_t)h) << 16); }

DEV void gload16(const void* g, void* l) {
  __builtin_amdgcn_global_load_lds(
      (const __attribute__((address_space(1))) void*)g,
      (__attribute__((address_space(3))) void*)l, 16, 0, 0);
}

// ---------------- cast x (fp32 -> bf16), 4 elems/thread ----------------
__global__ void k_cast4(const float* __restrict__ in, u16* __restrict__ out, int n4) {
  int i = blockIdx.x * blockDim.x + threadIdx.x;
  if (i >= n4) return;
  float4 v = ((const float4*)in)[i];
  uint2 p;
  p.x = (uint32_t)f2bf(v.x) | ((uint32_t)f2bf(v.y) << 16);
  p.y = (uint32_t)f2bf(v.z) | ((uint32_t)f2bf(v.w) << 16);
  ((uint2*)out)[i] = p;
}

// ------------- transpose + cast: W[K][N] fp32 -> Wt[N][K] bf16 ---------
__global__ void k_tcast(const float* __restrict__ Wm, u16* __restrict__ Wt, int K, int N) {
  __shared__ u16 t[64][65];
  int n0 = blockIdx.x * 64, k0 = blockIdx.y * 64;
  int tid = threadIdx.x;
#pragma unroll
  for (int i = 0; i < 16; ++i) {
    int idx = tid + i * 256, r = idx >> 6, c = idx & 63;
    t[r][c] = f2bf(Wm[(size_t)(k0 + r) * N + n0 + c]);
  }
  __syncthreads();
#pragma unroll
  for (int i = 0; i < 16; ++i) {
    int idx = tid + i * 256, r = idx >> 6, c = idx & 63;
    Wt[(size_t)(n0 + r) * K + k0 + c] = t[c][r];
  }
}

// ---- GEMM v4: 128x128 tile, BK=64, double-buffer, 4 waves -------------
template <int OUT_BF16>
__global__ __launch_bounds__(256) void k_gemm4(
    const u16* __restrict__ A, const u16* __restrict__ Bt,
    const float* __restrict__ bias, void* __restrict__ Cout,
    int M, int N, int K) {
  __shared__ __attribute__((aligned(16))) u16 S[2][2][128 * 64];  // 64 KiB
  int bid = blockIdx.x;
  int ntn = N >> 7;
  int cpx = gridDim.x >> 3;                       // grid % 8 == 0 always here
  int wg = (bid & 7) * cpx + (bid >> 3);          // bijective XCD chunking
  int my = wg / ntn, nx = wg - my * ntn;
  int m0 = my * 128, n0 = nx * 128;
  int tid = threadIdx.x, lane = tid & 63, w = tid >> 6;
  int wr = (w >> 1) * 64, wc = (w & 1) * 64;
  int lr = lane & 15, lg = lane >> 4;
  int rsw = (lr & 7) << 3;                        // read-side XOR (u16 units)
  int srow = tid >> 3;                            // stager: 8 thr/row (128 B)
  int scb = ((tid & 7) ^ ((tid >> 3) & 7)) * 8;   // pre-swizzled src col (u16)
  f32x4 acc[4][4];
#pragma unroll
  for (int i = 0; i < 4; ++i)
#pragma unroll
    for (int j = 0; j < 4; ++j) acc[i][j] = (f32x4){0.f, 0.f, 0.f, 0.f};

  int nk = K >> 6;

#define STG4(buf, kt)                                                                   \
  do {                                                                                  \
    gload16(A + (size_t)(m0 + srow) * K + (kt) * 64 + scb, &S[buf][0][tid * 8]);        \
    gload16(A + (size_t)(m0 + 32 + srow) * K + (kt) * 64 + scb, &S[buf][0][2048 + tid * 8]);  \
    gload16(A + (size_t)(m0 + 64 + srow) * K + (kt) * 64 + scb, &S[buf][0][4096 + tid * 8]);  \
    gload16(A + (size_t)(m0 + 96 + srow) * K + (kt) * 64 + scb, &S[buf][0][6144 + tid * 8]);  \
    gload16(Bt + (size_t)(n0 + srow) * K + (kt) * 64 + scb, &S[buf][1][tid * 8]);       \
    gload16(Bt + (size_t)(n0 + 32 + srow) * K + (kt) * 64 + scb, &S[buf][1][2048 + tid * 8]); \
    gload16(Bt + (size_t)(n0 + 64 + srow) * K + (kt) * 64 + scb, &S[buf][1][4096 + tid * 8]); \
    gload16(Bt + (size_t)(n0 + 96 + srow) * K + (kt) * 64 + scb, &S[buf][1][6144 + tid * 8]); \
  } while (0)

  STG4(0, 0);
  asm volatile("s_waitcnt vmcnt(0)" ::: "memory");
  __syncthreads();

  for (int t = 0; t < nk; ++t) {
    int cur = t & 1;
    if (t + 1 < nk) STG4(cur ^ 1, t + 1);
#pragma unroll
    for (int ks = 0; ks < 2; ++ks) {
      short8 af[4], bf[4];
#pragma unroll
      for (int mi = 0; mi < 4; ++mi)
        af[mi] = *(const short8*)&S[cur][0][((wr + mi * 16 + lr) * 64 + ks * 32 + lg * 8) ^ rsw];
#pragma unroll
      for (int ni = 0; ni < 4; ++ni)
        bf[ni] = *(const short8*)&S[cur][1][((wc + ni * 16 + lr) * 64 + ks * 32 + lg * 8) ^ rsw];
      __builtin_amdgcn_s_setprio(1);
#pragma unroll
      for (int mi = 0; mi < 4; ++mi)
#pragma unroll
        for (int ni = 0; ni < 4; ++ni)
          acc[mi][ni] = __builtin_amdgcn_mfma_f32_16x16x32_bf16(af[mi], bf[ni], acc[mi][ni], 0, 0, 0);
      __builtin_amdgcn_s_setprio(0);
    }
    asm volatile("s_waitcnt vmcnt(0)" ::: "memory");
    __syncthreads();
  }
#undef STG4

  int rg = lg * 4;
#pragma unroll
  for (int mi = 0; mi < 4; ++mi) {
#pragma unroll
    for (int ni = 0; ni < 4; ++ni) {
      int col = n0 + wc + ni * 16 + lr;
      float bv = bias[col];
#pragma unroll
      for (int j = 0; j < 4; ++j) {
        int row = m0 + wr + mi * 16 + rg + j;
        float o = acc[mi][ni][j] + bv;
        if (OUT_BF16) ((u16*)Cout)[(size_t)row * N + col] = f2bf(o);
        else ((float*)Cout)[(size_t)row * N + col] = o;
      }
    }
  }
}

// ------- LN over head_dim for Q,K; reshape to (B,H,S,D), 2 elems/lane --
__global__ void k_lnsplit2(const u16* __restrict__ qkv,
                           const float* __restrict__ qg, const float* __restrict__ qb,
                           const float* __restrict__ kg, const float* __restrict__ kb,
                           u16* __restrict__ Qn, u16* __restrict__ Kn) {
  int wv = blockIdx.x * 4 + (threadIdx.x >> 6);
  int lane = threadIdx.x & 63;
  int p = wv * 2 + (lane >> 5);   // pair id in [0, 65536)
  int ln32 = lane & 31;
  int h = p & 15, row = p >> 4;   // row = b*S + s in [0,4096)
  const u16* base = qkv + (size_t)row * 3072 + h * 64 + ln32 * 2;
  uint uq = *(const uint*)base;
  uint uk = *(const uint*)(base + 1024);
  float q0 = bf2f((u16)uq), q1 = bf2f((u16)(uq >> 16));
  float k0 = bf2f((u16)uk), k1 = bf2f((u16)(uk >> 16));
  float qs = q0 + q1, qs2 = q0 * q0 + q1 * q1;
  float ks = k0 + k1, ks2 = k0 * k0 + k1 * k1;
#pragma unroll
  for (int m = 16; m > 0; m >>= 1) {  // stays within each 32-lane half
    qs += __shfl_xor(qs, m, 64);
    qs2 += __shfl_xor(qs2, m, 64);
    ks += __shfl_xor(ks, m, 64);
    ks2 += __shfl_xor(ks2, m, 64);
  }
  float qm = qs * (1.f / 64), km = ks * (1.f / 64);
  float qv = qs2 * (1.f / 64) - qm * qm, kv = ks2 * (1.f / 64) - km * km;
  float qr = rsqrtf(qv + 1e-5f), kr = rsqrtf(kv + 1e-5f);
  float2 g2 = ((const float2*)qg)[ln32], b2 = ((const float2*)qb)[ln32];
  float2 kg2 = ((const float2*)kg)[ln32], kb2 = ((const float2*)kb)[ln32];
  int b = row >> 11, s = row & 2047;
  size_t o = ((size_t)(b * 16 + h) * 2048 + s) * 64 + ln32 * 2;
  const float QSCL = 0.125f * 1.44269504f;  // 1/sqrt(D) * log2(e)
  u16 oq0 = f2bf(((q0 - qm) * qr * g2.x + b2.x) * QSCL);
  u16 oq1 = f2bf(((q1 - qm) * qr * g2.y + b2.y) * QSCL);
  u16 ok0 = f2bf((k0 - km) * kr * kg2.x + kb2.x);
  u16 ok1 = f2bf((k1 - km) * kr * kg2.y + kb2.y);
  *(uint*)(Qn + o) = (uint)oq0 | ((uint)oq1 << 16);
  *(uint*)(Kn + o) = (uint)ok0 | ((uint)ok1 << 16);
}

// ------- V transpose: qkv V-section -> Vt[bh][d][s] bf16 ---------------
__global__ void k_vt(const u16* __restrict__ qkv, u16* __restrict__ Vt) {
  __shared__ u16 t[64][66];
  int bid = blockIdx.x;
  int bh = bid & 31, st = bid >> 5;
  int b = bh >> 4, h = bh & 15;
  int s0 = st * 64;
  int tid = threadIdx.x;
#pragma unroll
  for (int i = 0; i < 16; ++i) {
    int idx = tid + i * 256, r = idx >> 6, c = idx & 63;
    t[r][c] = qkv[(size_t)(b * 2048 + s0 + r) * 3072 + 2048 + h * 64 + c];
  }
  __syncthreads();
#pragma unroll
  for (int i = 0; i < 16; ++i) {
    int idx = tid + i * 256, d = idx >> 6, s = idx & 63;
    Vt[((size_t)bh * 64 + d) * 2048 + s0 + s] = t[s][d];
  }
}

// ----------------- sliding-window flash attention (v5) -----------------
// kt-split (2 waves/32-row Q-tile) + K-fragment double-buffer (named-set
// 2x unroll) + interior-tile fast path (no mask VALU) + no exp-shift
// (softmax is scale-invariant; s <= 11.6 so p = exp2(s) <= 3000, safe).
__global__ __launch_bounds__(128) void k_attn5(
    const u16* __restrict__ Qn, const u16* __restrict__ Kn,
    const u16* __restrict__ Vt, u16* __restrict__ attb) {
  __shared__ __attribute__((aligned(16))) char smem[10496];
  u16* Pl = (u16*)smem;              // 2 waves x 32x72 u16 = 9216 B (loop phase)
  float* comb = (float*)smem;        // 64 lanes x 40 f32 = 10240 B (epilogue)
  int bid = blockIdx.x;
  int xcd = bid & 7, idx = bid >> 3;       // idx in [0,256)
  int bh = xcd * 4 + (idx & 3);
  int qt = 63 - (idx >> 2);                // 32-row tile, big-first
  int w = threadIdx.x >> 6, lane = threadIdx.x & 63;
  int ln15 = lane & 15, lg = lane >> 4;
  int qlo = qt * 32;
  const u16* Qh = Qn + (size_t)bh * (2048 * 64);
  const u16* Kh = Kn + (size_t)bh * (2048 * 64);
  const u16* Vh = Vt + (size_t)bh * (64 * 2048);

  short8 qf[2][2];
#pragma unroll
  for (int qs = 0; qs < 2; ++qs)
#pragma unroll
    for (int h = 0; h < 2; ++h)
      qf[qs][h] = *(const short8*)(Qh + (size_t)(qlo + qs * 16 + ln15) * 64 + h * 32 + lg * 8);

  f32x4 oacc[2][4];  // [qs][dt]
#pragma unroll
  for (int qs = 0; qs < 2; ++qs)
#pragma unroll
    for (int dt = 0; dt < 4; ++dt) oacc[qs][dt] = (f32x4){0.f, 0.f, 0.f, 0.f};
  float lwp[2][4];
#pragma unroll
  for (int qs = 0; qs < 2; ++qs)
#pragma unroll
    for (int j = 0; j < 4; ++j) lwp[qs][j] = 0.f;

  int t0 = qlo >= 512 ? (qlo - 511) >> 6 : 0;
  int t1 = (qlo + 31) >> 6;

#define LOADK(KF, KT)                                                          \
  do {                                                                         \
    const u16* Kt_ = Kh + (size_t)(KT) * 4096;                                 \
    _Pragma("unroll") for (int c = 0; c < 4; ++c)                              \
      _Pragma("unroll") for (int h2 = 0; h2 < 2; ++h2)                         \
        KF[c][h2] = *(const short8*)(Kt_ + (size_t)(c * 16 + ln15) * 64 + h2 * 32 + lg * 8); \
  } while (0)

#define ABODY(KT, KF)                                                          \
  do {                                                                         \
    int kt6 = (KT) * 64;                                                       \
    short8 vf[4][2];                                                           \
    _Pragma("unroll") for (int dt = 0; dt < 4; ++dt)                           \
      _Pragma("unroll") for (int h2 = 0; h2 < 2; ++h2)                         \
        vf[dt][h2] = *(const short8*)(Vh + (size_t)(dt * 16 + ln15) * 2048 +   \
                                      kt6 + h2 * 32 + lg * 8);                 \
    f32x4 sf[2][4];                                                            \
    _Pragma("unroll") for (int qs = 0; qs < 2; ++qs)                           \
      _Pragma("unroll") for (int c = 0; c < 4; ++c) {                          \
        f32x4 z = (f32x4){0.f, 0.f, 0.f, 0.f};                                 \
        z = __builtin_amdgcn_mfma_f32_16x16x32_bf16(qf[qs][0], KF[c][0], z, 0, 0, 0); \
        sf[qs][c] = __builtin_amdgcn_mfma_f32_16x16x32_bf16(qf[qs][1], KF[c][1], z, 0, 0, 0); \
      }                                                                        \
    bool interior = (kt6 + 63 <= qlo) && (kt6 >= qlo - 480);                   \
    if (interior) {                                                            \
      _Pragma("unroll") for (int qs = 0; qs < 2; ++qs)                         \
        _Pragma("unroll") for (int c = 0; c < 4; ++c)                          \
          _Pragma("unroll") for (int j = 0; j < 4; ++j) {                      \
            float p = __builtin_amdgcn_exp2f(sf[qs][c][j]);                    \
            sf[qs][c][j] = p;                                                  \
            lwp[qs][j] += p;                                                   \
          }                                                                    \
    } else {                                                                   \
      _Pragma("unroll") for (int qs = 0; qs < 2; ++qs)                         \
        _Pragma("unroll") for (int c = 0; c < 4; ++c) {                        \
          int kk = kt6 + c * 16 + ln15;                                        \
          _Pragma("unroll") for (int j = 0; j < 4; ++j) {                      \
            int q = qlo + qs * 16 + lg * 4 + j;                                \
            bool msk = (kk > q) || ((q - kk) >= 512);                          \
            float p = __builtin_amdgcn_exp2f(msk ? -1e30f : sf[qs][c][j]);     \
            sf[qs][c][j] = p;                                                  \
            lwp[qs][j] += p;                                                   \
          }                                                                    \
        }                                                                      \
    }                                                                          \
    _Pragma("unroll") for (int qs = 0; qs < 2; ++qs)                           \
      _Pragma("unroll") for (int c = 0; c < 4; ++c)                            \
        _Pragma("unroll") for (int j = 0; j < 4; ++j) {                        \
          uint32_t u = __float_as_uint(sf[qs][c][j]);                          \
          Pl[w * 2304 + (qs * 16 + lg * 4 + j) * 72 + c * 16 + ln15] =         \
              (u16)((u + 0x8000u) >> 16);                                      \
        }                                                                      \
    _Pragma("unroll") for (int qs = 0; qs < 2; ++qs)                           \
      _Pragma("unroll") for (int h2 = 0; h2 < 2; ++h2) {                       \
        short8 pf = *(const short8*)&Pl[w * 2304 + (qs * 16 + ln15) * 72 + h2 * 32 + lg * 8]; \
        _Pragma("unroll") for (int dt = 0; dt < 4; ++dt)                       \
          oacc[qs][dt] = __builtin_amdgcn_mfma_f32_16x16x32_bf16(pf, vf[dt][h2], oacc[qs][dt], 0, 0, 0); \
      }                                                                        \
  } while (0)

  int kt = t0 + w;
  short8 kfA[4][2], kfB[4][2];
  if (kt <= t1) {
    LOADK(kfA, kt);
    while (kt <= t1) {
      if (kt + 2 <= t1) LOADK(kfB, kt + 2);
      ABODY(kt, kfA);
      if (kt + 2 <= t1) {
        if (kt + 4 <= t1) LOADK(kfA, kt + 4);
        ABODY(kt + 2, kfB);
      }
      kt += 4;
    }
  }
#undef LOADK
#undef ABODY

  // combine wave1 partials into wave0 (additive: shared static max)
  __syncthreads();
  if (w == 1) {
    int base = lane * 40;
#pragma unroll
    for (int qs = 0; qs < 2; ++qs) {
#pragma unroll
      for (int dt = 0; dt < 4; ++dt)
#pragma unroll
        for (int j = 0; j < 4; ++j) comb[base + (qs * 4 + dt) * 4 + j] = oacc[qs][dt][j];
#pragma unroll
      for (int j = 0; j < 4; ++j) comb[base + 32 + qs * 4 + j] = lwp[qs][j];
    }
  }
  __syncthreads();
  if (w == 0) {
    int base = lane * 40;
#pragma unroll
    for (int qs = 0; qs < 2; ++qs) {
#pragma unroll
      for (int dt = 0; dt < 4; ++dt)
#pragma unroll
        for (int j = 0; j < 4; ++j) oacc[qs][dt][j] += comb[base + (qs * 4 + dt) * 4 + j];
#pragma unroll
      for (int j = 0; j < 4; ++j) lwp[qs][j] += comb[base + 32 + qs * 4 + j];
    }
    int b = bh >> 4, hh = bh & 15;
#pragma unroll
    for (int qs = 0; qs < 2; ++qs)
#pragma unroll
      for (int j = 0; j < 4; ++j) {
        float rs = lwp[qs][j];
#pragma unroll
        for (int m = 8; m > 0; m >>= 1) rs += __shfl_xor(rs, m, 64);
        float inv = rs > 0.f ? 1.f / rs : 0.f;
        int row = b * 2048 + qlo + qs * 16 + lg * 4 + j;
#pragma unroll
        for (int dt = 0; dt < 4; ++dt)
          attb[(size_t)row * 1024 + hh * 64 + dt * 16 + ln15] = f2bf(oacc[qs][dt][j] * inv);
      }
  }
}

extern "C" void kernel_launch(void* const* d_in, const int* in_sizes, int n_in,
                              void* d_out, int out_size, void* d_ws, size_t ws_size,
                              hipStream_t stream) {
  const float* x = (const float*)d_in[0];
  const float* Wqkv = (const float*)d_in[1];
  const float* bqkv = (const float*)d_in[2];
  const float* qg = (const float*)d_in[3];
  const float* qb = (const float*)d_in[4];
  const float* kg = (const float*)d_in[5];
  const float* kb = (const float*)d_in[6];
  const float* Wout = (const float*)d_in[7];
  const float* bout = (const float*)d_in[8];
  float* out = (float*)d_out;

  char* ws = (char*)d_ws;
  u16* qkvb = (u16*)(ws);                    // 4096x3072 bf16 = 25,165,824 B
  u16* attb = (u16*)(ws);                    // aliases dead qkvb
  u16* Qn = (u16*)(ws + 25165824);           // 8,388,608
  u16* Kn = (u16*)(ws + 33554432);           // 8,388,608
  u16* xb = (u16*)(ws + 41943040);           // 8,388,608
  u16* Vt = xb;                              // aliases dead xb (V^T per head)
  u16* wqkvT = (u16*)(ws + 50331648);        // 6,291,456
  u16* woutT = (u16*)(ws + 56623104);        // 2,097,152  (total 58,720,256)

  // 1. casts / transposes
  k_cast4<<<4096, 256, 0, stream>>>(x, xb, 4194304 / 4);
  k_tcast<<<dim3(48, 16), 256, 0, stream>>>(Wqkv, wqkvT, 1024, 3072);
  k_tcast<<<dim3(16, 16), 256, 0, stream>>>(Wout, woutT, 1024, 1024);
  // 2. QKV GEMM (+bias) -> bf16  (BK=64 dbuf)
  k_gemm4<1><<<768, 256, 0, stream>>>(xb, wqkvT, bqkv, qkvb, 4096, 3072, 1024);
  // 3. qk-norm + reshape to (B,H,S,D); V transpose to (B,H,D,S)
  k_lnsplit2<<<8192, 256, 0, stream>>>(qkvb, qg, qb, kg, kb, Qn, Kn);
  k_vt<<<1024, 256, 0, stream>>>(qkvb, Vt);
  // 4. sliding-window attention -> (B,S,E) bf16
  k_attn5<<<2048, 128, 0, stream>>>(Qn, Kn, Vt, attb);
  // 5. output GEMM (+bias) -> fp32
  k_gemm4<0><<<256, 256, 0, stream>>>(attb, woutT, bout, out, 4096, 1024, 1024);
}

// Round 9
// 110.019 us; speedup vs baseline: 1.1420x; 1.1420x over previous
//
#include <hip/hip_runtime.h>
#include <stdint.h>

typedef uint16_t u16;
typedef __attribute__((ext_vector_type(8))) short short8;
typedef __attribute__((ext_vector_type(4))) float f32x4;

#define DEV static __device__ __forceinline__

DEV u16 f2bf(float f) {
  uint32_t u = __float_as_uint(f);
  return (u16)((u + 0x7fffu + ((u >> 16) & 1u)) >> 16);
}
DEV float bf2f(u16 h) { return __uint_as_float(((uint32_t)h) << 16); }

DEV void gload16(const void* g, void* l) {
  __builtin_amdgcn_global_load_lds(
      (const __attribute__((address_space(1))) void*)g,
      (__attribute__((address_space(3))) void*)l, 16, 0, 0);
}

// ---------------- cast x (fp32 -> bf16), 4 elems/thread ----------------
__global__ void k_cast4(const float* __restrict__ in, u16* __restrict__ out, int n4) {
  int i = blockIdx.x * blockDim.x + threadIdx.x;
  if (i >= n4) return;
  float4 v = ((const float4*)in)[i];
  uint2 p;
  p.x = (uint32_t)f2bf(v.x) | ((uint32_t)f2bf(v.y) << 16);
  p.y = (uint32_t)f2bf(v.z) | ((uint32_t)f2bf(v.w) << 16);
  ((uint2*)out)[i] = p;
}

// ------------- transpose + cast: W[K][N] fp32 -> Wt[N][K] bf16 ---------
__global__ void k_tcast(const float* __restrict__ Wm, u16* __restrict__ Wt, int K, int N) {
  __shared__ u16 t[64][65];
  int n0 = blockIdx.x * 64, k0 = blockIdx.y * 64;
  int tid = threadIdx.x;
#pragma unroll
  for (int i = 0; i < 16; ++i) {
    int idx = tid + i * 256, r = idx >> 6, c = idx & 63;
    t[r][c] = f2bf(Wm[(size_t)(k0 + r) * N + n0 + c]);
  }
  __syncthreads();
#pragma unroll
  for (int i = 0; i < 16; ++i) {
    int idx = tid + i * 256, r = idx >> 6, c = idx & 63;
    Wt[(size_t)(n0 + r) * K + k0 + c] = t[c][r];
  }
}

// ---- GEMM v4: 128x128 tile, BK=64, double-buffer, 4 waves -------------
template <int OUT_BF16>
__global__ __launch_bounds__(256) void k_gemm4(
    const u16* __restrict__ A, const u16* __restrict__ Bt,
    const float* __restrict__ bias, void* __restrict__ Cout,
    int M, int N, int K) {
  __shared__ __attribute__((aligned(16))) u16 S[2][2][128 * 64];  // 64 KiB
  int bid = blockIdx.x;
  int ntn = N >> 7;
  int cpx = gridDim.x >> 3;                       // grid % 8 == 0 always here
  int wg = (bid & 7) * cpx + (bid >> 3);          // bijective XCD chunking
  int my = wg / ntn, nx = wg - my * ntn;
  int m0 = my * 128, n0 = nx * 128;
  int tid = threadIdx.x, lane = tid & 63, w = tid >> 6;
  int wr = (w >> 1) * 64, wc = (w & 1) * 64;
  int lr = lane & 15, lg = lane >> 4;
  int rsw = (lr & 7) << 3;                        // read-side XOR (u16 units)
  int srow = tid >> 3;                            // stager: 8 thr/row (128 B)
  int scb = ((tid & 7) ^ ((tid >> 3) & 7)) * 8;   // pre-swizzled src col (u16)
  f32x4 acc[4][4];
#pragma unroll
  for (int i = 0; i < 4; ++i)
#pragma unroll
    for (int j = 0; j < 4; ++j) acc[i][j] = (f32x4){0.f, 0.f, 0.f, 0.f};

  int nk = K >> 6;

#define STG4(buf, kt)                                                                   \
  do {                                                                                  \
    gload16(A + (size_t)(m0 + srow) * K + (kt) * 64 + scb, &S[buf][0][tid * 8]);        \
    gload16(A + (size_t)(m0 + 32 + srow) * K + (kt) * 64 + scb, &S[buf][0][2048 + tid * 8]);  \
    gload16(A + (size_t)(m0 + 64 + srow) * K + (kt) * 64 + scb, &S[buf][0][4096 + tid * 8]);  \
    gload16(A + (size_t)(m0 + 96 + srow) * K + (kt) * 64 + scb, &S[buf][0][6144 + tid * 8]);  \
    gload16(Bt + (size_t)(n0 + srow) * K + (kt) * 64 + scb, &S[buf][1][tid * 8]);       \
    gload16(Bt + (size_t)(n0 + 32 + srow) * K + (kt) * 64 + scb, &S[buf][1][2048 + tid * 8]); \
    gload16(Bt + (size_t)(n0 + 64 + srow) * K + (kt) * 64 + scb, &S[buf][1][4096 + tid * 8]); \
    gload16(Bt + (size_t)(n0 + 96 + srow) * K + (kt) * 64 + scb, &S[buf][1][6144 + tid * 8]); \
  } while (0)

  STG4(0, 0);
  asm volatile("s_waitcnt vmcnt(0)" ::: "memory");
  __syncthreads();

  for (int t = 0; t < nk; ++t) {
    int cur = t & 1;
    if (t + 1 < nk) STG4(cur ^ 1, t + 1);
#pragma unroll
    for (int ks = 0; ks < 2; ++ks) {
      short8 af[4], bf[4];
#pragma unroll
      for (int mi = 0; mi < 4; ++mi)
        af[mi] = *(const short8*)&S[cur][0][((wr + mi * 16 + lr) * 64 + ks * 32 + lg * 8) ^ rsw];
#pragma unroll
      for (int ni = 0; ni < 4; ++ni)
        bf[ni] = *(const short8*)&S[cur][1][((wc + ni * 16 + lr) * 64 + ks * 32 + lg * 8) ^ rsw];
      __builtin_amdgcn_s_setprio(1);
#pragma unroll
      for (int mi = 0; mi < 4; ++mi)
#pragma unroll
        for (int ni = 0; ni < 4; ++ni)
          acc[mi][ni] = __builtin_amdgcn_mfma_f32_16x16x32_bf16(af[mi], bf[ni], acc[mi][ni], 0, 0, 0);
      __builtin_amdgcn_s_setprio(0);
    }
    asm volatile("s_waitcnt vmcnt(0)" ::: "memory");
    __syncthreads();
  }
#undef STG4

  int rg = lg * 4;
#pragma unroll
  for (int mi = 0; mi < 4; ++mi) {
#pragma unroll
    for (int ni = 0; ni < 4; ++ni) {
      int col = n0 + wc + ni * 16 + lr;
      float bv = bias[col];
#pragma unroll
      for (int j = 0; j < 4; ++j) {
        int row = m0 + wr + mi * 16 + rg + j;
        float o = acc[mi][ni][j] + bv;
        if (OUT_BF16) ((u16*)Cout)[(size_t)row * N + col] = f2bf(o);
        else ((float*)Cout)[(size_t)row * N + col] = o;
      }
    }
  }
}

// ------- LN over head_dim for Q,K; reshape to (B,H,S,D), 2 elems/lane --
__global__ void k_lnsplit2(const u16* __restrict__ qkv,
                           const float* __restrict__ qg, const float* __restrict__ qb,
                           const float* __restrict__ kg, const float* __restrict__ kb,
                           u16* __restrict__ Qn, u16* __restrict__ Kn) {
  int wv = blockIdx.x * 4 + (threadIdx.x >> 6);
  int lane = threadIdx.x & 63;
  int p = wv * 2 + (lane >> 5);   // pair id in [0, 65536)
  int ln32 = lane & 31;
  int h = p & 15, row = p >> 4;   // row = b*S + s in [0,4096)
  const u16* base = qkv + (size_t)row * 3072 + h * 64 + ln32 * 2;
  uint uq = *(const uint*)base;
  uint uk = *(const uint*)(base + 1024);
  float q0 = bf2f((u16)uq), q1 = bf2f((u16)(uq >> 16));
  float k0 = bf2f((u16)uk), k1 = bf2f((u16)(uk >> 16));
  float qs = q0 + q1, qs2 = q0 * q0 + q1 * q1;
  float ks = k0 + k1, ks2 = k0 * k0 + k1 * k1;
#pragma unroll
  for (int m = 16; m > 0; m >>= 1) {  // stays within each 32-lane half
    qs += __shfl_xor(qs, m, 64);
    qs2 += __shfl_xor(qs2, m, 64);
    ks += __shfl_xor(ks, m, 64);
    ks2 += __shfl_xor(ks2, m, 64);
  }
  float qm = qs * (1.f / 64), km = ks * (1.f / 64);
  float qv = qs2 * (1.f / 64) - qm * qm, kv = ks2 * (1.f / 64) - km * km;
  float qr = rsqrtf(qv + 1e-5f), kr = rsqrtf(kv + 1e-5f);
  float2 g2 = ((const float2*)qg)[ln32], b2 = ((const float2*)qb)[ln32];
  float2 kg2 = ((const float2*)kg)[ln32], kb2 = ((const float2*)kb)[ln32];
  int b = row >> 11, s = row & 2047;
  size_t o = ((size_t)(b * 16 + h) * 2048 + s) * 64 + ln32 * 2;
  const float QSCL = 0.125f * 1.44269504f;  // 1/sqrt(D) * log2(e)
  u16 oq0 = f2bf(((q0 - qm) * qr * g2.x + b2.x) * QSCL);
  u16 oq1 = f2bf(((q1 - qm) * qr * g2.y + b2.y) * QSCL);
  u16 ok0 = f2bf((k0 - km) * kr * kg2.x + kb2.x);
  u16 ok1 = f2bf((k1 - km) * kr * kg2.y + kb2.y);
  *(uint*)(Qn + o) = (uint)oq0 | ((uint)oq1 << 16);
  *(uint*)(Kn + o) = (uint)ok0 | ((uint)ok1 << 16);
}

// ------- V transpose: qkv V-section -> Vt[bh][d][s] bf16 ---------------
__global__ void k_vt(const u16* __restrict__ qkv, u16* __restrict__ Vt) {
  __shared__ u16 t[64][66];
  int bid = blockIdx.x;
  int bh = bid & 31, st = bid >> 5;
  int b = bh >> 4, h = bh & 15;
  int s0 = st * 64;
  int tid = threadIdx.x;
#pragma unroll
  for (int i = 0; i < 16; ++i) {
    int idx = tid + i * 256, r = idx >> 6, c = idx & 63;
    t[r][c] = qkv[(size_t)(b * 2048 + s0 + r) * 3072 + 2048 + h * 64 + c];
  }
  __syncthreads();
#pragma unroll
  for (int i = 0; i < 16; ++i) {
    int idx = tid + i * 256, d = idx >> 6, s = idx & 63;
    Vt[((size_t)bh * 64 + d) * 2048 + s0 + s] = t[s][d];
  }
}

// ----------------- sliding-window flash attention (v6) -----------------
// GEMM4-shaped: block = 4 waves / 64 q-rows of one (b,h); wave owns 16
// rows (no kt-split, no combine). Per K-tile: K-tile + Vt-tile staged to
// double-buffered LDS via gload16 (4/thread), involution-swizzled
// (HW-verified conflict-free), ONE vmcnt(0)+barrier per tile issued
// before ~700cy of compute. Fragments from LDS (~12cy) not global L2
// (~300cy); K/V read once per BLOCK not per wave. Static-max softmax.
__global__ __launch_bounds__(256) void k_attn6(
    const u16* __restrict__ Qn, const u16* __restrict__ Kn,
    const u16* __restrict__ Vt, u16* __restrict__ attb) {
  __shared__ __attribute__((aligned(16))) u16 KL[2][4096];  // [key][d] swz
  __shared__ __attribute__((aligned(16))) u16 VL[2][4096];  // [d][key] swz
  __shared__ __attribute__((aligned(16))) u16 Pl[4][16 * 72];
  int bid = blockIdx.x;
  int xcd = bid & 7, idx = bid >> 3;     // idx in [0,128)
  int bh = xcd * 4 + (idx & 3);
  int qt = 31 - (idx >> 2);              // 64-row tile, big-first
  int q0 = qt * 64;
  int tid = threadIdx.x, lane = tid & 63, w = tid >> 6;
  int ln15 = lane & 15, lg = lane >> 4;
  int qlo = q0 + w * 16;                 // wave's 16 q rows
  const u16* Qh = Qn + (size_t)bh * (2048 * 64);
  const u16* Kh = Kn + (size_t)bh * (2048 * 64);
  const u16* Vh = Vt + (size_t)bh * (64 * 2048);
  int rsw = (ln15 & 7) << 3;             // read-side XOR (u16 units)
  int srow = tid >> 3;                   // stager: 8 thr/row, 32 rows/gload
  int scb = ((tid & 7) ^ ((tid >> 3) & 7)) * 8;

  short8 qf[2];
#pragma unroll
  for (int h2 = 0; h2 < 2; ++h2)
    qf[h2] = *(const short8*)(Qh + (size_t)(qlo + ln15) * 64 + h2 * 32 + lg * 8);

  f32x4 oacc[4];
#pragma unroll
  for (int dt = 0; dt < 4; ++dt) oacc[dt] = (f32x4){0.f, 0.f, 0.f, 0.f};
  float lwp[4] = {0.f, 0.f, 0.f, 0.f};

  int t0 = q0 >= 512 ? (q0 - 511) >> 6 : 0;
  int t1 = (q0 + 63) >> 6;

#define STAGE_A6(buf, kt)                                                              \
  do {                                                                                 \
    const u16* Kt_ = Kh + (size_t)(kt) * 4096;                                         \
    gload16(Kt_ + (size_t)srow * 64 + scb, &KL[buf][tid * 8]);                         \
    gload16(Kt_ + (size_t)(srow + 32) * 64 + scb, &KL[buf][2048 + tid * 8]);           \
    const u16* Vt_ = Vh + (size_t)(kt) * 64;                                           \
    gload16(Vt_ + (size_t)srow * 2048 + scb, &VL[buf][tid * 8]);                       \
    gload16(Vt_ + (size_t)(srow + 32) * 2048 + scb, &VL[buf][2048 + tid * 8]);         \
  } while (0)

  STAGE_A6(0, t0);
  asm volatile("s_waitcnt vmcnt(0)" ::: "memory");
  __syncthreads();

  for (int t = t0; t <= t1; ++t) {
    int cur = (t - t0) & 1;
    if (t + 1 <= t1) STAGE_A6(cur ^ 1, t + 1);
    int kt6 = t * 64;
    // wave-uniform: does this tile intersect this wave's window?
    if (kt6 <= qlo + 15 && kt6 + 63 >= qlo - 511) {
      short8 kf[4][2];
#pragma unroll
      for (int c = 0; c < 4; ++c)
#pragma unroll
        for (int h2 = 0; h2 < 2; ++h2)
          kf[c][h2] = *(const short8*)&KL[cur][((c * 16 + ln15) * 64 + h2 * 32 + lg * 8) ^ rsw];
      f32x4 sf[4];
      __builtin_amdgcn_s_setprio(1);
#pragma unroll
      for (int c = 0; c < 4; ++c) {
        f32x4 z = (f32x4){0.f, 0.f, 0.f, 0.f};
        z = __builtin_amdgcn_mfma_f32_16x16x32_bf16(qf[0], kf[c][0], z, 0, 0, 0);
        sf[c] = __builtin_amdgcn_mfma_f32_16x16x32_bf16(qf[1], kf[c][1], z, 0, 0, 0);
      }
      __builtin_amdgcn_s_setprio(0);
      bool interior = (kt6 + 63 <= qlo) && (kt6 >= qlo - 496);
      if (interior) {
#pragma unroll
        for (int c = 0; c < 4; ++c)
#pragma unroll
          for (int j = 0; j < 4; ++j) {
            float p = __builtin_amdgcn_exp2f(sf[c][j]);
            sf[c][j] = p;
            lwp[j] += p;
          }
      } else {
#pragma unroll
        for (int c = 0; c < 4; ++c) {
          int kk = kt6 + c * 16 + ln15;
#pragma unroll
          for (int j = 0; j < 4; ++j) {
            int q = qlo + lg * 4 + j;
            bool msk = (kk > q) || ((q - kk) >= 512);
            float p = __builtin_amdgcn_exp2f(msk ? -1e30f : sf[c][j]);
            sf[c][j] = p;
            lwp[j] += p;
          }
        }
      }
#pragma unroll
      for (int c = 0; c < 4; ++c)
#pragma unroll
        for (int j = 0; j < 4; ++j) {
          uint32_t u = __float_as_uint(sf[c][j]);
          Pl[w][(lg * 4 + j) * 72 + c * 16 + ln15] = (u16)((u + 0x8000u) >> 16);
        }
      short8 vf[4][2];
#pragma unroll
      for (int dt = 0; dt < 4; ++dt)
#pragma unroll
        for (int h2 = 0; h2 < 2; ++h2)
          vf[dt][h2] = *(const short8*)&VL[cur][((dt * 16 + ln15) * 64 + h2 * 32 + lg * 8) ^ rsw];
      __builtin_amdgcn_s_setprio(1);
#pragma unroll
      for (int h2 = 0; h2 < 2; ++h2) {
        short8 pf = *(const short8*)&Pl[w][ln15 * 72 + h2 * 32 + lg * 8];
#pragma unroll
        for (int dt = 0; dt < 4; ++dt)
          oacc[dt] = __builtin_amdgcn_mfma_f32_16x16x32_bf16(pf, vf[dt][h2], oacc[dt], 0, 0, 0);
      }
      __builtin_amdgcn_s_setprio(0);
    }
    asm volatile("s_waitcnt vmcnt(0)" ::: "memory");
    __syncthreads();
  }
#undef STAGE_A6

  // epilogue: reduce row sums over the 16 col-lanes, normalize, write
  int b = bh >> 4, hh = bh & 15;
#pragma unroll
  for (int j = 0; j < 4; ++j) {
    float rs = lwp[j];
#pragma unroll
    for (int m = 8; m > 0; m >>= 1) rs += __shfl_xor(rs, m, 64);
    float inv = rs > 0.f ? 1.f / rs : 0.f;
    int row = b * 2048 + qlo + lg * 4 + j;
#pragma unroll
    for (int dt = 0; dt < 4; ++dt)
      attb[(size_t)row * 1024 + hh * 64 + dt * 16 + ln15] = f2bf(oacc[dt][j] * inv);
  }
}

extern "C" void kernel_launch(void* const* d_in, const int* in_sizes, int n_in,
                              void* d_out, int out_size, void* d_ws, size_t ws_size,
                              hipStream_t stream) {
  const float* x = (const float*)d_in[0];
  const float* Wqkv = (const float*)d_in[1];
  const float* bqkv = (const float*)d_in[2];
  const float* qg = (const float*)d_in[3];
  const float* qb = (const float*)d_in[4];
  const float* kg = (const float*)d_in[5];
  const float* kb = (const float*)d_in[6];
  const float* Wout = (const float*)d_in[7];
  const float* bout = (const float*)d_in[8];
  float* out = (float*)d_out;

  char* ws = (char*)d_ws;
  u16* qkvb = (u16*)(ws);                    // 4096x3072 bf16 = 25,165,824 B
  u16* attb = (u16*)(ws);                    // aliases dead qkvb
  u16* Qn = (u16*)(ws + 25165824);           // 8,388,608
  u16* Kn = (u16*)(ws + 33554432);           // 8,388,608
  u16* xb = (u16*)(ws + 41943040);           // 8,388,608
  u16* Vt = xb;                              // aliases dead xb (V^T per head)
  u16* wqkvT = (u16*)(ws + 50331648);        // 6,291,456
  u16* woutT = (u16*)(ws + 56623104);        // 2,097,152  (total 58,720,256)

  // 1. casts / transposes
  k_cast4<<<4096, 256, 0, stream>>>(x, xb, 4194304 / 4);
  k_tcast<<<dim3(48, 16), 256, 0, stream>>>(Wqkv, wqkvT, 1024, 3072);
  k_tcast<<<dim3(16, 16), 256, 0, stream>>>(Wout, woutT, 1024, 1024);
  // 2. QKV GEMM (+bias) -> bf16  (BK=64 dbuf)
  k_gemm4<1><<<768, 256, 0, stream>>>(xb, wqkvT, bqkv, qkvb, 4096, 3072, 1024);
  // 3. qk-norm + reshape to (B,H,S,D); V transpose to (B,H,D,S)
  k_lnsplit2<<<8192, 256, 0, stream>>>(qkvb, qg, qb, kg, kb, Qn, Kn);
  k_vt<<<1024, 256, 0, stream>>>(qkvb, Vt);
  // 4. sliding-window attention -> (B,S,E) bf16
  k_attn6<<<1024, 256, 0, stream>>>(Qn, Kn, Vt, attb);
  // 5. output GEMM (+bias) -> fp32
  k_gemm4<0><<<256, 256, 0, stream>>>(attb, woutT, bout, out, 4096, 1024, 1024);
}

// Round 10
// 100.034 us; speedup vs baseline: 1.2560x; 1.0998x over previous
//
#include <hip/hip_runtime.h>
#include <stdint.h>

typedef uint16_t u16;
typedef __attribute__((ext_vector_type(8))) short short8;
typedef __attribute__((ext_vector_type(4))) float f32x4;

#define DEV static __device__ __forceinline__

DEV u16 f2bf(float f) {
  uint32_t u = __float_as_uint(f);
  return (u16)((u + 0x7fffu + ((u >> 16) & 1u)) >> 16);
}
DEV float bf2f(u16 h) { return __uint_as_float(((uint32_t)h) << 16); }

DEV void gload16(const void* g, void* l) {
  __builtin_amdgcn_global_load_lds(
      (const __attribute__((address_space(1))) void*)g,
      (__attribute__((address_space(3))) void*)l, 16, 0, 0);
}

// ---------------- cast x (fp32 -> bf16), 4 elems/thread ----------------
__global__ void k_cast4(const float* __restrict__ in, u16* __restrict__ out, int n4) {
  int i = blockIdx.x * blockDim.x + threadIdx.x;
  if (i >= n4) return;
  float4 v = ((const float4*)in)[i];
  uint2 p;
  p.x = (uint32_t)f2bf(v.x) | ((uint32_t)f2bf(v.y) << 16);
  p.y = (uint32_t)f2bf(v.z) | ((uint32_t)f2bf(v.w) << 16);
  ((uint2*)out)[i] = p;
}

// ------------- transpose + cast: W[K][N] fp32 -> Wt[N][K] bf16 ---------
__global__ void k_tcast(const float* __restrict__ Wm, u16* __restrict__ Wt, int K, int N) {
  __shared__ u16 t[64][65];
  int n0 = blockIdx.x * 64, k0 = blockIdx.y * 64;
  int tid = threadIdx.x;
#pragma unroll
  for (int i = 0; i < 16; ++i) {
    int idx = tid + i * 256, r = idx >> 6, c = idx & 63;
    t[r][c] = f2bf(Wm[(size_t)(k0 + r) * N + n0 + c]);
  }
  __syncthreads();
#pragma unroll
  for (int i = 0; i < 16; ++i) {
    int idx = tid + i * 256, r = idx >> 6, c = idx & 63;
    Wt[(size_t)(n0 + r) * K + k0 + c] = t[c][r];
  }
}

// ---- fused QKV GEMM + qk-LN + head-split + V-transpose ----------------
// gemm4 structure (128x128, BK=64, dbuf, 4 waves). Each wave's 64-col
// span = exactly one head (sections 1024-aligned). Epilogue: LN over d
// on f32 accs (16-lane shfl_xor reduce), write Qn/Kn in (B,H,S,D);
// V fragments stored directly to Vt[bh][d][s] as 8B packed stores.
// qkvb intermediate eliminated (-50MB HBM round-trip, -2 launches).
__global__ __launch_bounds__(256) void k_gemmqkv(
    const u16* __restrict__ A, const u16* __restrict__ Bt,
    const float* __restrict__ bias,
    const float* __restrict__ qg, const float* __restrict__ qb,
    const float* __restrict__ kg, const float* __restrict__ kb,
    u16* __restrict__ Qn, u16* __restrict__ Kn, u16* __restrict__ Vt) {
  const int K = 1024, N = 3072;
  __shared__ __attribute__((aligned(16))) u16 S[2][2][128 * 64];  // 64 KiB
  int bid = blockIdx.x;
  int ntn = N >> 7;                               // 24
  int cpx = gridDim.x >> 3;                       // 96
  int wg = (bid & 7) * cpx + (bid >> 3);          // bijective XCD chunking
  int my = wg / ntn, nx = wg - my * ntn;
  int m0 = my * 128, n0 = nx * 128;
  int tid = threadIdx.x, lane = tid & 63, w = tid >> 6;
  int wr = (w >> 1) * 64, wc = (w & 1) * 64;
  int lr = lane & 15, lg = lane >> 4;
  int rsw = (lr & 7) << 3;
  int srow = tid >> 3;
  int scb = ((tid & 7) ^ ((tid >> 3) & 7)) * 8;
  f32x4 acc[4][4];
#pragma unroll
  for (int i = 0; i < 4; ++i)
#pragma unroll
    for (int j = 0; j < 4; ++j) acc[i][j] = (f32x4){0.f, 0.f, 0.f, 0.f};

  int nk = K >> 6;

#define STGQ(buf, kt)                                                                   \
  do {                                                                                  \
    gload16(A + (size_t)(m0 + srow) * K + (kt) * 64 + scb, &S[buf][0][tid * 8]);        \
    gload16(A + (size_t)(m0 + 32 + srow) * K + (kt) * 64 + scb, &S[buf][0][2048 + tid * 8]);  \
    gload16(A + (size_t)(m0 + 64 + srow) * K + (kt) * 64 + scb, &S[buf][0][4096 + tid * 8]);  \
    gload16(A + (size_t)(m0 + 96 + srow) * K + (kt) * 64 + scb, &S[buf][0][6144 + tid * 8]);  \
    gload16(Bt + (size_t)(n0 + srow) * K + (kt) * 64 + scb, &S[buf][1][tid * 8]);       \
    gload16(Bt + (size_t)(n0 + 32 + srow) * K + (kt) * 64 + scb, &S[buf][1][2048 + tid * 8]); \
    gload16(Bt + (size_t)(n0 + 64 + srow) * K + (kt) * 64 + scb, &S[buf][1][4096 + tid * 8]); \
    gload16(Bt + (size_t)(n0 + 96 + srow) * K + (kt) * 64 + scb, &S[buf][1][6144 + tid * 8]); \
  } while (0)

  STGQ(0, 0);
  asm volatile("s_waitcnt vmcnt(0)" ::: "memory");
  __syncthreads();

  for (int t = 0; t < nk; ++t) {
    int cur = t & 1;
    if (t + 1 < nk) STGQ(cur ^ 1, t + 1);
#pragma unroll
    for (int ks = 0; ks < 2; ++ks) {
      short8 af[4], bf[4];
#pragma unroll
      for (int mi = 0; mi < 4; ++mi)
        af[mi] = *(const short8*)&S[cur][0][((wr + mi * 16 + lr) * 64 + ks * 32 + lg * 8) ^ rsw];
#pragma unroll
      for (int ni = 0; ni < 4; ++ni)
        bf[ni] = *(const short8*)&S[cur][1][((wc + ni * 16 + lr) * 64 + ks * 32 + lg * 8) ^ rsw];
      __builtin_amdgcn_s_setprio(1);
#pragma unroll
      for (int mi = 0; mi < 4; ++mi)
#pragma unroll
        for (int ni = 0; ni < 4; ++ni)
          acc[mi][ni] = __builtin_amdgcn_mfma_f32_16x16x32_bf16(af[mi], bf[ni], acc[mi][ni], 0, 0, 0);
      __builtin_amdgcn_s_setprio(0);
    }
    asm volatile("s_waitcnt vmcnt(0)" ::: "memory");
    __syncthreads();
  }
#undef STGQ

  int rg = lg * 4;
  int sec = n0 >> 10;                       // 0=Q, 1=K, 2=V
  int hh = ((n0 + wc) >> 6) & 15;           // head for this wave
  int b = m0 >> 11;
  int s0 = m0 & 2047;

  if (sec < 2) {
    const float* gp = sec ? kg : qg;
    const float* bp = sec ? kb : qb;
    float scl = sec ? 1.f : (0.125f * 1.44269504f);  // Q: fold 1/sqrt(D)*log2e
    u16* op = sec ? Kn : Qn;
    float gv[4], bev[4], bb[4];
#pragma unroll
    for (int ni = 0; ni < 4; ++ni) {
      int d = ni * 16 + lr;
      gv[ni] = gp[d];
      bev[ni] = bp[d];
      bb[ni] = bias[n0 + wc + d];
    }
    size_t hb = (size_t)(b * 16 + hh) * 2048 * 64;
#pragma unroll
    for (int mi = 0; mi < 4; ++mi) {
      float a[4][4], ps[4], ps2[4];
#pragma unroll
      for (int ni = 0; ni < 4; ++ni)
#pragma unroll
        for (int j = 0; j < 4; ++j) a[ni][j] = acc[mi][ni][j] + bb[ni];
#pragma unroll
      for (int j = 0; j < 4; ++j) {
        ps[j] = a[0][j] + a[1][j] + a[2][j] + a[3][j];
        ps2[j] = a[0][j] * a[0][j] + a[1][j] * a[1][j] + a[2][j] * a[2][j] + a[3][j] * a[3][j];
      }
#pragma unroll
      for (int m = 1; m < 16; m <<= 1)
#pragma unroll
        for (int j = 0; j < 4; ++j) {
          ps[j] += __shfl_xor(ps[j], m, 64);
          ps2[j] += __shfl_xor(ps2[j], m, 64);
        }
#pragma unroll
      for (int j = 0; j < 4; ++j) {
        float mean = ps[j] * (1.f / 64);
        float var = ps2[j] * (1.f / 64) - mean * mean;
        float r = rsqrtf(var + 1e-5f);
        int row = s0 + wr + mi * 16 + rg + j;
        size_t base = hb + (size_t)row * 64;
#pragma unroll
        for (int ni = 0; ni < 4; ++ni) {
          float v = ((a[ni][j] - mean) * r * gv[ni] + bev[ni]) * scl;
          op[base + ni * 16 + lr] = f2bf(v);
        }
      }
    }
  } else {
    // V: direct transposed store Vt[bh][d][s], 8B packed (4 consecutive s)
    u16* vbase = Vt + (size_t)(b * 16 + hh) * 64 * 2048;
#pragma unroll
    for (int ni = 0; ni < 4; ++ni) {
      int d = ni * 16 + lr;
      float bb = bias[n0 + wc + d];
#pragma unroll
      for (int mi = 0; mi < 4; ++mi) {
        int row0 = s0 + wr + mi * 16 + rg;
        uint2 pk;
        pk.x = (uint32_t)f2bf(acc[mi][ni][0] + bb) | ((uint32_t)f2bf(acc[mi][ni][1] + bb) << 16);
        pk.y = (uint32_t)f2bf(acc[mi][ni][2] + bb) | ((uint32_t)f2bf(acc[mi][ni][3] + bb) << 16);
        *(uint2*)(vbase + (size_t)d * 2048 + row0) = pk;
      }
    }
  }
}

// ---- GEMM v4: 128x128 tile, BK=64, double-buffer, 4 waves (GEMM2) -----
template <int OUT_BF16>
__global__ __launch_bounds__(256) void k_gemm4(
    const u16* __restrict__ A, const u16* __restrict__ Bt,
    const float* __restrict__ bias, void* __restrict__ Cout,
    int M, int N, int K) {
  __shared__ __attribute__((aligned(16))) u16 S[2][2][128 * 64];  // 64 KiB
  int bid = blockIdx.x;
  int ntn = N >> 7;
  int cpx = gridDim.x >> 3;
  int wg = (bid & 7) * cpx + (bid >> 3);
  int my = wg / ntn, nx = wg - my * ntn;
  int m0 = my * 128, n0 = nx * 128;
  int tid = threadIdx.x, lane = tid & 63, w = tid >> 6;
  int wr = (w >> 1) * 64, wc = (w & 1) * 64;
  int lr = lane & 15, lg = lane >> 4;
  int rsw = (lr & 7) << 3;
  int srow = tid >> 3;
  int scb = ((tid & 7) ^ ((tid >> 3) & 7)) * 8;
  f32x4 acc[4][4];
#pragma unroll
  for (int i = 0; i < 4; ++i)
#pragma unroll
    for (int j = 0; j < 4; ++j) acc[i][j] = (f32x4){0.f, 0.f, 0.f, 0.f};

  int nk = K >> 6;

#define STG4(buf, kt)                                                                   \
  do {                                                                                  \
    gload16(A + (size_t)(m0 + srow) * K + (kt) * 64 + scb, &S[buf][0][tid * 8]);        \
    gload16(A + (size_t)(m0 + 32 + srow) * K + (kt) * 64 + scb, &S[buf][0][2048 + tid * 8]);  \
    gload16(A + (size_t)(m0 + 64 + srow) * K + (kt) * 64 + scb, &S[buf][0][4096 + tid * 8]);  \
    gload16(A + (size_t)(m0 + 96 + srow) * K + (kt) * 64 + scb, &S[buf][0][6144 + tid * 8]);  \
    gload16(Bt + (size_t)(n0 + srow) * K + (kt) * 64 + scb, &S[buf][1][tid * 8]);       \
    gload16(Bt + (size_t)(n0 + 32 + srow) * K + (kt) * 64 + scb, &S[buf][1][2048 + tid * 8]); \
    gload16(Bt + (size_t)(n0 + 64 + srow) * K + (kt) * 64 + scb, &S[buf][1][4096 + tid * 8]); \
    gload16(Bt + (size_t)(n0 + 96 + srow) * K + (kt) * 64 + scb, &S[buf][1][6144 + tid * 8]); \
  } while (0)

  STG4(0, 0);
  asm volatile("s_waitcnt vmcnt(0)" ::: "memory");
  __syncthreads();

  for (int t = 0; t < nk; ++t) {
    int cur = t & 1;
    if (t + 1 < nk) STG4(cur ^ 1, t + 1);
#pragma unroll
    for (int ks = 0; ks < 2; ++ks) {
      short8 af[4], bf[4];
#pragma unroll
      for (int mi = 0; mi < 4; ++mi)
        af[mi] = *(const short8*)&S[cur][0][((wr + mi * 16 + lr) * 64 + ks * 32 + lg * 8) ^ rsw];
#pragma unroll
      for (int ni = 0; ni < 4; ++ni)
        bf[ni] = *(const short8*)&S[cur][1][((wc + ni * 16 + lr) * 64 + ks * 32 + lg * 8) ^ rsw];
      __builtin_amdgcn_s_setprio(1);
#pragma unroll
      for (int mi = 0; mi < 4; ++mi)
#pragma unroll
        for (int ni = 0; ni < 4; ++ni)
          acc[mi][ni] = __builtin_amdgcn_mfma_f32_16x16x32_bf16(af[mi], bf[ni], acc[mi][ni], 0, 0, 0);
      __builtin_amdgcn_s_setprio(0);
    }
    asm volatile("s_waitcnt vmcnt(0)" ::: "memory");
    __syncthreads();
  }
#undef STG4

  int rg = lg * 4;
#pragma unroll
  for (int mi = 0; mi < 4; ++mi) {
#pragma unroll
    for (int ni = 0; ni < 4; ++ni) {
      int col = n0 + wc + ni * 16 + lr;
      float bv = bias[col];
#pragma unroll
      for (int j = 0; j < 4; ++j) {
        int row = m0 + wr + mi * 16 + rg + j;
        float o = acc[mi][ni][j] + bv;
        if (OUT_BF16) ((u16*)Cout)[(size_t)row * N + col] = f2bf(o);
        else ((float*)Cout)[(size_t)row * N + col] = o;
      }
    }
  }
}

// ----------------- sliding-window flash attention (v6) -----------------
__global__ __launch_bounds__(256) void k_attn6(
    const u16* __restrict__ Qn, const u16* __restrict__ Kn,
    const u16* __restrict__ Vt, u16* __restrict__ attb) {
  __shared__ __attribute__((aligned(16))) u16 KL[2][4096];  // [key][d] swz
  __shared__ __attribute__((aligned(16))) u16 VL[2][4096];  // [d][key] swz
  __shared__ __attribute__((aligned(16))) u16 Pl[4][16 * 72];
  int bid = blockIdx.x;
  int xcd = bid & 7, idx = bid >> 3;     // idx in [0,128)
  int bh = xcd * 4 + (idx & 3);
  int qt = 31 - (idx >> 2);              // 64-row tile, big-first
  int q0 = qt * 64;
  int tid = threadIdx.x, lane = tid & 63, w = tid >> 6;
  int ln15 = lane & 15, lg = lane >> 4;
  int qlo = q0 + w * 16;                 // wave's 16 q rows
  const u16* Qh = Qn + (size_t)bh * (2048 * 64);
  const u16* Kh = Kn + (size_t)bh * (2048 * 64);
  const u16* Vh = Vt + (size_t)bh * (64 * 2048);
  int rsw = (ln15 & 7) << 3;
  int srow = tid >> 3;
  int scb = ((tid & 7) ^ ((tid >> 3) & 7)) * 8;

  short8 qf[2];
#pragma unroll
  for (int h2 = 0; h2 < 2; ++h2)
    qf[h2] = *(const short8*)(Qh + (size_t)(qlo + ln15) * 64 + h2 * 32 + lg * 8);

  f32x4 oacc[4];
#pragma unroll
  for (int dt = 0; dt < 4; ++dt) oacc[dt] = (f32x4){0.f, 0.f, 0.f, 0.f};
  float lwp[4] = {0.f, 0.f, 0.f, 0.f};

  int t0 = q0 >= 512 ? (q0 - 511) >> 6 : 0;
  int t1 = (q0 + 63) >> 6;

#define STAGE_A6(buf, kt)                                                              \
  do {                                                                                 \
    const u16* Kt_ = Kh + (size_t)(kt) * 4096;                                         \
    gload16(Kt_ + (size_t)srow * 64 + scb, &KL[buf][tid * 8]);                         \
    gload16(Kt_ + (size_t)(srow + 32) * 64 + scb, &KL[buf][2048 + tid * 8]);           \
    const u16* Vt_ = Vh + (size_t)(kt) * 64;                                           \
    gload16(Vt_ + (size_t)srow * 2048 + scb, &VL[buf][tid * 8]);                       \
    gload16(Vt_ + (size_t)(srow + 32) * 2048 + scb, &VL[buf][2048 + tid * 8]);         \
  } while (0)

  STAGE_A6(0, t0);
  asm volatile("s_waitcnt vmcnt(0)" ::: "memory");
  __syncthreads();

  for (int t = t0; t <= t1; ++t) {
    int cur = (t - t0) & 1;
    if (t + 1 <= t1) STAGE_A6(cur ^ 1, t + 1);
    int kt6 = t * 64;
    if (kt6 <= qlo + 15 && kt6 + 63 >= qlo - 511) {
      short8 kf[4][2];
#pragma unroll
      for (int c = 0; c < 4; ++c)
#pragma unroll
        for (int h2 = 0; h2 < 2; ++h2)
          kf[c][h2] = *(const short8*)&KL[cur][((c * 16 + ln15) * 64 + h2 * 32 + lg * 8) ^ rsw];
      f32x4 sf[4];
      __builtin_amdgcn_s_setprio(1);
#pragma unroll
      for (int c = 0; c < 4; ++c) {
        f32x4 z = (f32x4){0.f, 0.f, 0.f, 0.f};
        z = __builtin_amdgcn_mfma_f32_16x16x32_bf16(qf[0], kf[c][0], z, 0, 0, 0);
        sf[c] = __builtin_amdgcn_mfma_f32_16x16x32_bf16(qf[1], kf[c][1], z, 0, 0, 0);
      }
      __builtin_amdgcn_s_setprio(0);
      bool interior = (kt6 + 63 <= qlo) && (kt6 >= qlo - 496);
      if (interior) {
#pragma unroll
        for (int c = 0; c < 4; ++c)
#pragma unroll
          for (int j = 0; j < 4; ++j) {
            float p = __builtin_amdgcn_exp2f(sf[c][j]);
            sf[c][j] = p;
            lwp[j] += p;
          }
      } else {
#pragma unroll
        for (int c = 0; c < 4; ++c) {
          int kk = kt6 + c * 16 + ln15;
#pragma unroll
          for (int j = 0; j < 4; ++j) {
            int q = qlo + lg * 4 + j;
            bool msk = (kk > q) || ((q - kk) >= 512);
            float p = __builtin_amdgcn_exp2f(msk ? -1e30f : sf[c][j]);
            sf[c][j] = p;
            lwp[j] += p;
          }
        }
      }
#pragma unroll
      for (int c = 0; c < 4; ++c)
#pragma unroll
        for (int j = 0; j < 4; ++j) {
          uint32_t u = __float_as_uint(sf[c][j]);
          Pl[w][(lg * 4 + j) * 72 + c * 16 + ln15] = (u16)((u + 0x8000u) >> 16);
        }
      short8 vf[4][2];
#pragma unroll
      for (int dt = 0; dt < 4; ++dt)
#pragma unroll
        for (int h2 = 0; h2 < 2; ++h2)
          vf[dt][h2] = *(const short8*)&VL[cur][((dt * 16 + ln15) * 64 + h2 * 32 + lg * 8) ^ rsw];
      __builtin_amdgcn_s_setprio(1);
#pragma unroll
      for (int h2 = 0; h2 < 2; ++h2) {
        short8 pf = *(const short8*)&Pl[w][ln15 * 72 + h2 * 32 + lg * 8];
#pragma unroll
        for (int dt = 0; dt < 4; ++dt)
          oacc[dt] = __builtin_amdgcn_mfma_f32_16x16x32_bf16(pf, vf[dt][h2], oacc[dt], 0, 0, 0);
      }
      __builtin_amdgcn_s_setprio(0);
    }
    asm volatile("s_waitcnt vmcnt(0)" ::: "memory");
    __syncthreads();
  }
#undef STAGE_A6

  int b = bh >> 4, hh = bh & 15;
#pragma unroll
  for (int j = 0; j < 4; ++j) {
    float rs = lwp[j];
#pragma unroll
    for (int m = 8; m > 0; m >>= 1) rs += __shfl_xor(rs, m, 64);
    float inv = rs > 0.f ? 1.f / rs : 0.f;
    int row = b * 2048 + qlo + lg * 4 + j;
#pragma unroll
    for (int dt = 0; dt < 4; ++dt)
      attb[(size_t)row * 1024 + hh * 64 + dt * 16 + ln15] = f2bf(oacc[dt][j] * inv);
  }
}

extern "C" void kernel_launch(void* const* d_in, const int* in_sizes, int n_in,
                              void* d_out, int out_size, void* d_ws, size_t ws_size,
                              hipStream_t stream) {
  const float* x = (const float*)d_in[0];
  const float* Wqkv = (const float*)d_in[1];
  const float* bqkv = (const float*)d_in[2];
  const float* qg = (const float*)d_in[3];
  const float* qb = (const float*)d_in[4];
  const float* kg = (const float*)d_in[5];
  const float* kb = (const float*)d_in[6];
  const float* Wout = (const float*)d_in[7];
  const float* bout = (const float*)d_in[8];
  float* out = (float*)d_out;

  char* ws = (char*)d_ws;
  u16* attb = (u16*)(ws);                    // 8,388,608
  u16* Vt = (u16*)(ws + 8388608);            // 8,388,608 (NO aliasing: written
  u16* Qn = (u16*)(ws + 16777216);           //  concurrently with xb reads)
  u16* Kn = (u16*)(ws + 25165824);           // 8,388,608
  u16* xb = (u16*)(ws + 33554432);           // 8,388,608
  u16* wqkvT = (u16*)(ws + 41943040);        // 6,291,456
  u16* woutT = (u16*)(ws + 48234496);        // 2,097,152  (total 50,331,648)

  // 1. casts / transposes
  k_cast4<<<4096, 256, 0, stream>>>(x, xb, 4194304 / 4);
  k_tcast<<<dim3(48, 16), 256, 0, stream>>>(Wqkv, wqkvT, 1024, 3072);
  k_tcast<<<dim3(16, 16), 256, 0, stream>>>(Wout, woutT, 1024, 1024);
  // 2. fused QKV GEMM + bias + qk-LN + head-split + V-transpose
  k_gemmqkv<<<768, 256, 0, stream>>>(xb, wqkvT, bqkv, qg, qb, kg, kb, Qn, Kn, Vt);
  // 3. sliding-window attention -> (B,S,E) bf16
  k_attn6<<<1024, 256, 0, stream>>>(Qn, Kn, Vt, attb);
  // 4. output GEMM (+bias) -> fp32
  k_gemm4<0><<<256, 256, 0, stream>>>(attb, woutT, bout, out, 4096, 1024, 1024);
}

// Round 11
// 99.743 us; speedup vs baseline: 1.2597x; 1.0029x over previous
//
#include <hip/hip_runtime.h>
#include <stdint.h>

typedef uint16_t u16;
typedef __attribute__((ext_vector_type(8))) short short8;
typedef __attribute__((ext_vector_type(4))) float f32x4;

#define DEV static __device__ __forceinline__

DEV u16 f2bf(float f) {
  uint32_t u = __float_as_uint(f);
  return (u16)((u + 0x7fffu + ((u >> 16) & 1u)) >> 16);
}
DEV float bf2f(u16 h) { return __uint_as_float(((uint32_t)h) << 16); }

DEV void gload16(const void* g, void* l) {
  __builtin_amdgcn_global_load_lds(
      (const __attribute__((address_space(1))) void*)g,
      (__attribute__((address_space(3))) void*)l, 16, 0, 0);
}

// ---------------- cast x (fp32 -> bf16), 4 elems/thread ----------------
__global__ void k_cast4(const float* __restrict__ in, u16* __restrict__ out, int n4) {
  int i = blockIdx.x * blockDim.x + threadIdx.x;
  if (i >= n4) return;
  float4 v = ((const float4*)in)[i];
  uint2 p;
  p.x = (uint32_t)f2bf(v.x) | ((uint32_t)f2bf(v.y) << 16);
  p.y = (uint32_t)f2bf(v.z) | ((uint32_t)f2bf(v.w) << 16);
  ((uint2*)out)[i] = p;
}

// ------------- transpose + cast: W[K][N] fp32 -> Wt[N][K] bf16 ---------
__global__ void k_tcast(const float* __restrict__ Wm, u16* __restrict__ Wt, int K, int N) {
  __shared__ u16 t[64][65];
  int n0 = blockIdx.x * 64, k0 = blockIdx.y * 64;
  int tid = threadIdx.x;
#pragma unroll
  for (int i = 0; i < 16; ++i) {
    int idx = tid + i * 256, r = idx >> 6, c = idx & 63;
    t[r][c] = f2bf(Wm[(size_t)(k0 + r) * N + n0 + c]);
  }
  __syncthreads();
#pragma unroll
  for (int i = 0; i < 16; ++i) {
    int idx = tid + i * 256, r = idx >> 6, c = idx & 63;
    Wt[(size_t)(n0 + r) * K + k0 + c] = t[c][r];
  }
}

// ---- fused QKV GEMM + qk-LN + head-split + V-transpose ----------------
__global__ __launch_bounds__(256) void k_gemmqkv(
    const u16* __restrict__ A, const u16* __restrict__ Bt,
    const float* __restrict__ bias,
    const float* __restrict__ qg, const float* __restrict__ qb,
    const float* __restrict__ kg, const float* __restrict__ kb,
    u16* __restrict__ Qn, u16* __restrict__ Kn, u16* __restrict__ Vt) {
  const int K = 1024, N = 3072;
  __shared__ __attribute__((aligned(16))) u16 S[2][2][128 * 64];  // 64 KiB
  int bid = blockIdx.x;
  int ntn = N >> 7;                               // 24
  int cpx = gridDim.x >> 3;                       // 96
  int wg = (bid & 7) * cpx + (bid >> 3);          // bijective XCD chunking
  int my = wg / ntn, nx = wg - my * ntn;
  int m0 = my * 128, n0 = nx * 128;
  int tid = threadIdx.x, lane = tid & 63, w = tid >> 6;
  int wr = (w >> 1) * 64, wc = (w & 1) * 64;
  int lr = lane & 15, lg = lane >> 4;
  int rsw = (lr & 7) << 3;
  int srow = tid >> 3;
  int scb = ((tid & 7) ^ ((tid >> 3) & 7)) * 8;
  f32x4 acc[4][4];
#pragma unroll
  for (int i = 0; i < 4; ++i)
#pragma unroll
    for (int j = 0; j < 4; ++j) acc[i][j] = (f32x4){0.f, 0.f, 0.f, 0.f};

  int nk = K >> 6;

#define STGQ(buf, kt)                                                                   \
  do {                                                                                  \
    gload16(A + (size_t)(m0 + srow) * K + (kt) * 64 + scb, &S[buf][0][tid * 8]);        \
    gload16(A + (size_t)(m0 + 32 + srow) * K + (kt) * 64 + scb, &S[buf][0][2048 + tid * 8]);  \
    gload16(A + (size_t)(m0 + 64 + srow) * K + (kt) * 64 + scb, &S[buf][0][4096 + tid * 8]);  \
    gload16(A + (size_t)(m0 + 96 + srow) * K + (kt) * 64 + scb, &S[buf][0][6144 + tid * 8]);  \
    gload16(Bt + (size_t)(n0 + srow) * K + (kt) * 64 + scb, &S[buf][1][tid * 8]);       \
    gload16(Bt + (size_t)(n0 + 32 + srow) * K + (kt) * 64 + scb, &S[buf][1][2048 + tid * 8]); \
    gload16(Bt + (size_t)(n0 + 64 + srow) * K + (kt) * 64 + scb, &S[buf][1][4096 + tid * 8]); \
    gload16(Bt + (size_t)(n0 + 96 + srow) * K + (kt) * 64 + scb, &S[buf][1][6144 + tid * 8]); \
  } while (0)

  STGQ(0, 0);
  asm volatile("s_waitcnt vmcnt(0)" ::: "memory");
  __syncthreads();

  for (int t = 0; t < nk; ++t) {
    int cur = t & 1;
    if (t + 1 < nk) STGQ(cur ^ 1, t + 1);
#pragma unroll
    for (int ks = 0; ks < 2; ++ks) {
      short8 af[4], bf[4];
#pragma unroll
      for (int mi = 0; mi < 4; ++mi)
        af[mi] = *(const short8*)&S[cur][0][((wr + mi * 16 + lr) * 64 + ks * 32 + lg * 8) ^ rsw];
#pragma unroll
      for (int ni = 0; ni < 4; ++ni)
        bf[ni] = *(const short8*)&S[cur][1][((wc + ni * 16 + lr) * 64 + ks * 32 + lg * 8) ^ rsw];
      __builtin_amdgcn_s_setprio(1);
#pragma unroll
      for (int mi = 0; mi < 4; ++mi)
#pragma unroll
        for (int ni = 0; ni < 4; ++ni)
          acc[mi][ni] = __builtin_amdgcn_mfma_f32_16x16x32_bf16(af[mi], bf[ni], acc[mi][ni], 0, 0, 0);
      __builtin_amdgcn_s_setprio(0);
    }
    asm volatile("s_waitcnt vmcnt(0)" ::: "memory");
    __syncthreads();
  }
#undef STGQ

  int rg = lg * 4;
  int sec = n0 >> 10;                       // 0=Q, 1=K, 2=V
  int hh = ((n0 + wc) >> 6) & 15;           // head for this wave
  int b = m0 >> 11;
  int s0 = m0 & 2047;

  if (sec < 2) {
    const float* gp = sec ? kg : qg;
    const float* bp = sec ? kb : qb;
    float scl = sec ? 1.f : (0.125f * 1.44269504f);  // Q: fold 1/sqrt(D)*log2e
    u16* op = sec ? Kn : Qn;
    float gv[4], bev[4], bb[4];
#pragma unroll
    for (int ni = 0; ni < 4; ++ni) {
      int d = ni * 16 + lr;
      gv[ni] = gp[d];
      bev[ni] = bp[d];
      bb[ni] = bias[n0 + wc + d];
    }
    size_t hb = (size_t)(b * 16 + hh) * 2048 * 64;
#pragma unroll
    for (int mi = 0; mi < 4; ++mi) {
      float a[4][4], ps[4], ps2[4];
#pragma unroll
      for (int ni = 0; ni < 4; ++ni)
#pragma unroll
        for (int j = 0; j < 4; ++j) a[ni][j] = acc[mi][ni][j] + bb[ni];
#pragma unroll
      for (int j = 0; j < 4; ++j) {
        ps[j] = a[0][j] + a[1][j] + a[2][j] + a[3][j];
        ps2[j] = a[0][j] * a[0][j] + a[1][j] * a[1][j] + a[2][j] * a[2][j] + a[3][j] * a[3][j];
      }
#pragma unroll
      for (int m = 1; m < 16; m <<= 1)
#pragma unroll
        for (int j = 0; j < 4; ++j) {
          ps[j] += __shfl_xor(ps[j], m, 64);
          ps2[j] += __shfl_xor(ps2[j], m, 64);
        }
#pragma unroll
      for (int j = 0; j < 4; ++j) {
        float mean = ps[j] * (1.f / 64);
        float var = ps2[j] * (1.f / 64) - mean * mean;
        float r = rsqrtf(var + 1e-5f);
        int row = s0 + wr + mi * 16 + rg + j;
        size_t base = hb + (size_t)row * 64;
#pragma unroll
        for (int ni = 0; ni < 4; ++ni) {
          float v = ((a[ni][j] - mean) * r * gv[ni] + bev[ni]) * scl;
          op[base + ni * 16 + lr] = f2bf(v);
        }
      }
    }
  } else {
    // V: direct transposed store Vt[bh][d][s], 8B packed (4 consecutive s)
    u16* vbase = Vt + (size_t)(b * 16 + hh) * 64 * 2048;
#pragma unroll
    for (int ni = 0; ni < 4; ++ni) {
      int d = ni * 16 + lr;
      float bb = bias[n0 + wc + d];
#pragma unroll
      for (int mi = 0; mi < 4; ++mi) {
        int row0 = s0 + wr + mi * 16 + rg;
        uint2 pk;
        pk.x = (uint32_t)f2bf(acc[mi][ni][0] + bb) | ((uint32_t)f2bf(acc[mi][ni][1] + bb) << 16);
        pk.y = (uint32_t)f2bf(acc[mi][ni][2] + bb) | ((uint32_t)f2bf(acc[mi][ni][3] + bb) << 16);
        *(uint2*)(vbase + (size_t)d * 2048 + row0) = pk;
      }
    }
  }
}

// ---- GEMM v4: 128x128 tile, BK=64, double-buffer, 4 waves (GEMM2) -----
template <int OUT_BF16>
__global__ __launch_bounds__(256) void k_gemm4(
    const u16* __restrict__ A, const u16* __restrict__ Bt,
    const float* __restrict__ bias, void* __restrict__ Cout,
    int M, int N, int K) {
  __shared__ __attribute__((aligned(16))) u16 S[2][2][128 * 64];  // 64 KiB
  int bid = blockIdx.x;
  int ntn = N >> 7;
  int cpx = gridDim.x >> 3;
  int wg = (bid & 7) * cpx + (bid >> 3);
  int my = wg / ntn, nx = wg - my * ntn;
  int m0 = my * 128, n0 = nx * 128;
  int tid = threadIdx.x, lane = tid & 63, w = tid >> 6;
  int wr = (w >> 1) * 64, wc = (w & 1) * 64;
  int lr = lane & 15, lg = lane >> 4;
  int rsw = (lr & 7) << 3;
  int srow = tid >> 3;
  int scb = ((tid & 7) ^ ((tid >> 3) & 7)) * 8;
  f32x4 acc[4][4];
#pragma unroll
  for (int i = 0; i < 4; ++i)
#pragma unroll
    for (int j = 0; j < 4; ++j) acc[i][j] = (f32x4){0.f, 0.f, 0.f, 0.f};

  int nk = K >> 6;

#define STG4(buf, kt)                                                                   \
  do {                                                                                  \
    gload16(A + (size_t)(m0 + srow) * K + (kt) * 64 + scb, &S[buf][0][tid * 8]);        \
    gload16(A + (size_t)(m0 + 32 + srow) * K + (kt) * 64 + scb, &S[buf][0][2048 + tid * 8]);  \
    gload16(A + (size_t)(m0 + 64 + srow) * K + (kt) * 64 + scb, &S[buf][0][4096 + tid * 8]);  \
    gload16(A + (size_t)(m0 + 96 + srow) * K + (kt) * 64 + scb, &S[buf][0][6144 + tid * 8]);  \
    gload16(Bt + (size_t)(n0 + srow) * K + (kt) * 64 + scb, &S[buf][1][tid * 8]);       \
    gload16(Bt + (size_t)(n0 + 32 + srow) * K + (kt) * 64 + scb, &S[buf][1][2048 + tid * 8]); \
    gload16(Bt + (size_t)(n0 + 64 + srow) * K + (kt) * 64 + scb, &S[buf][1][4096 + tid * 8]); \
    gload16(Bt + (size_t)(n0 + 96 + srow) * K + (kt) * 64 + scb, &S[buf][1][6144 + tid * 8]); \
  } while (0)

  STG4(0, 0);
  asm volatile("s_waitcnt vmcnt(0)" ::: "memory");
  __syncthreads();

  for (int t = 0; t < nk; ++t) {
    int cur = t & 1;
    if (t + 1 < nk) STG4(cur ^ 1, t + 1);
#pragma unroll
    for (int ks = 0; ks < 2; ++ks) {
      short8 af[4], bf[4];
#pragma unroll
      for (int mi = 0; mi < 4; ++mi)
        af[mi] = *(const short8*)&S[cur][0][((wr + mi * 16 + lr) * 64 + ks * 32 + lg * 8) ^ rsw];
#pragma unroll
      for (int ni = 0; ni < 4; ++ni)
        bf[ni] = *(const short8*)&S[cur][1][((wc + ni * 16 + lr) * 64 + ks * 32 + lg * 8) ^ rsw];
      __builtin_amdgcn_s_setprio(1);
#pragma unroll
      for (int mi = 0; mi < 4; ++mi)
#pragma unroll
        for (int ni = 0; ni < 4; ++ni)
          acc[mi][ni] = __builtin_amdgcn_mfma_f32_16x16x32_bf16(af[mi], bf[ni], acc[mi][ni], 0, 0, 0);
      __builtin_amdgcn_s_setprio(0);
    }
    asm volatile("s_waitcnt vmcnt(0)" ::: "memory");
    __syncthreads();
  }
#undef STG4

  int rg = lg * 4;
#pragma unroll
  for (int mi = 0; mi < 4; ++mi) {
#pragma unroll
    for (int ni = 0; ni < 4; ++ni) {
      int col = n0 + wc + ni * 16 + lr;
      float bv = bias[col];
#pragma unroll
      for (int j = 0; j < 4; ++j) {
        int row = m0 + wr + mi * 16 + rg + j;
        float o = acc[mi][ni][j] + bv;
        if (OUT_BF16) ((u16*)Cout)[(size_t)row * N + col] = f2bf(o);
        else ((float*)Cout)[(size_t)row * N + col] = o;
      }
    }
  }
}

// ----------------- sliding-window flash attention (v7) -----------------
// attn6 structure with 2x per-wave Q-rows: block = 4 waves x 32 rows =
// 128 q-rows of one (b,h); 512 blocks. Same staged K/V tile now feeds
// 32 MFMA/wave (was 16); stage traffic + barriers per unit work halved.
__global__ __launch_bounds__(256) void k_attn7(
    const u16* __restrict__ Qn, const u16* __restrict__ Kn,
    const u16* __restrict__ Vt, u16* __restrict__ attb) {
  __shared__ __attribute__((aligned(16))) u16 KL[2][4096];  // [key][d] swz
  __shared__ __attribute__((aligned(16))) u16 VL[2][4096];  // [d][key] swz
  __shared__ __attribute__((aligned(16))) u16 Pl[4][2304];  // per-wave 32x72
  int bid = blockIdx.x;
  int xcd = bid & 7, idx = bid >> 3;     // idx in [0,64)
  int bh = xcd * 4 + (idx & 3);
  int qb = 15 - (idx >> 2);              // 128-row tile, big-first
  int q0 = qb * 128;
  int tid = threadIdx.x, lane = tid & 63, w = tid >> 6;
  int ln15 = lane & 15, lg = lane >> 4;
  int qlo = q0 + w * 32;                 // wave's 32 q rows
  const u16* Qh = Qn + (size_t)bh * (2048 * 64);
  const u16* Kh = Kn + (size_t)bh * (2048 * 64);
  const u16* Vh = Vt + (size_t)bh * (64 * 2048);
  int rsw = (ln15 & 7) << 3;
  int srow = tid >> 3;
  int scb = ((tid & 7) ^ ((tid >> 3) & 7)) * 8;

  short8 qf[2][2];
#pragma unroll
  for (int qs = 0; qs < 2; ++qs)
#pragma unroll
    for (int h2 = 0; h2 < 2; ++h2)
      qf[qs][h2] = *(const short8*)(Qh + (size_t)(qlo + qs * 16 + ln15) * 64 + h2 * 32 + lg * 8);

  f32x4 oacc[2][4];
#pragma unroll
  for (int qs = 0; qs < 2; ++qs)
#pragma unroll
    for (int dt = 0; dt < 4; ++dt) oacc[qs][dt] = (f32x4){0.f, 0.f, 0.f, 0.f};
  float lwp[2][4];
#pragma unroll
  for (int qs = 0; qs < 2; ++qs)
#pragma unroll
    for (int j = 0; j < 4; ++j) lwp[qs][j] = 0.f;

  int t0 = q0 >= 512 ? (q0 - 511) >> 6 : 0;
  int t1 = (q0 + 127) >> 6;

#define STAGE_A7(buf, kt)                                                              \
  do {                                                                                 \
    const u16* Kt_ = Kh + (size_t)(kt) * 4096;                                         \
    gload16(Kt_ + (size_t)srow * 64 + scb, &KL[buf][tid * 8]);                         \
    gload16(Kt_ + (size_t)(srow + 32) * 64 + scb, &KL[buf][2048 + tid * 8]);           \
    const u16* Vt_ = Vh + (size_t)(kt) * 64;                                           \
    gload16(Vt_ + (size_t)srow * 2048 + scb, &VL[buf][tid * 8]);                       \
    gload16(Vt_ + (size_t)(srow + 32) * 2048 + scb, &VL[buf][2048 + tid * 8]);         \
  } while (0)

  STAGE_A7(0, t0);
  asm volatile("s_waitcnt vmcnt(0)" ::: "memory");
  __syncthreads();

  for (int t = t0; t <= t1; ++t) {
    int cur = (t - t0) & 1;
    if (t + 1 <= t1) STAGE_A7(cur ^ 1, t + 1);
    int kt6 = t * 64;
    // wave-uniform: tile intersects this wave's 32-row window?
    if (kt6 <= qlo + 31 && kt6 + 63 >= qlo - 511) {
      short8 kf[4][2];
#pragma unroll
      for (int c = 0; c < 4; ++c)
#pragma unroll
        for (int h2 = 0; h2 < 2; ++h2)
          kf[c][h2] = *(const short8*)&KL[cur][((c * 16 + ln15) * 64 + h2 * 32 + lg * 8) ^ rsw];
      f32x4 sf[2][4];
      __builtin_amdgcn_s_setprio(1);
#pragma unroll
      for (int qs = 0; qs < 2; ++qs)
#pragma unroll
        for (int c = 0; c < 4; ++c) {
          f32x4 z = (f32x4){0.f, 0.f, 0.f, 0.f};
          z = __builtin_amdgcn_mfma_f32_16x16x32_bf16(qf[qs][0], kf[c][0], z, 0, 0, 0);
          sf[qs][c] = __builtin_amdgcn_mfma_f32_16x16x32_bf16(qf[qs][1], kf[c][1], z, 0, 0, 0);
        }
      __builtin_amdgcn_s_setprio(0);
      bool interior = (kt6 + 63 <= qlo) && (kt6 >= qlo - 480);
      if (interior) {
#pragma unroll
        for (int qs = 0; qs < 2; ++qs)
#pragma unroll
          for (int c = 0; c < 4; ++c)
#pragma unroll
            for (int j = 0; j < 4; ++j) {
              float p = __builtin_amdgcn_exp2f(sf[qs][c][j]);
              sf[qs][c][j] = p;
              lwp[qs][j] += p;
            }
      } else {
#pragma unroll
        for (int qs = 0; qs < 2; ++qs)
#pragma unroll
          for (int c = 0; c < 4; ++c) {
            int kk = kt6 + c * 16 + ln15;
#pragma unroll
            for (int j = 0; j < 4; ++j) {
              int q = qlo + qs * 16 + lg * 4 + j;
              bool msk = (kk > q) || ((q - kk) >= 512);
              float p = __builtin_amdgcn_exp2f(msk ? -1e30f : sf[qs][c][j]);
              sf[qs][c][j] = p;
              lwp[qs][j] += p;
            }
          }
      }
#pragma unroll
      for (int qs = 0; qs < 2; ++qs)
#pragma unroll
        for (int c = 0; c < 4; ++c)
#pragma unroll
          for (int j = 0; j < 4; ++j) {
            uint32_t u = __float_as_uint(sf[qs][c][j]);
            Pl[w][(qs * 16 + lg * 4 + j) * 72 + c * 16 + ln15] = (u16)((u + 0x8000u) >> 16);
          }
      short8 vf[4][2];
#pragma unroll
      for (int dt = 0; dt < 4; ++dt)
#pragma unroll
        for (int h2 = 0; h2 < 2; ++h2)
          vf[dt][h2] = *(const short8*)&VL[cur][((dt * 16 + ln15) * 64 + h2 * 32 + lg * 8) ^ rsw];
      __builtin_amdgcn_s_setprio(1);
#pragma unroll
      for (int qs = 0; qs < 2; ++qs)
#pragma unroll
        for (int h2 = 0; h2 < 2; ++h2) {
          short8 pf = *(const short8*)&Pl[w][(qs * 16 + ln15) * 72 + h2 * 32 + lg * 8];
#pragma unroll
          for (int dt = 0; dt < 4; ++dt)
            oacc[qs][dt] = __builtin_amdgcn_mfma_f32_16x16x32_bf16(pf, vf[dt][h2], oacc[qs][dt], 0, 0, 0);
        }
      __builtin_amdgcn_s_setprio(0);
    }
    asm volatile("s_waitcnt vmcnt(0)" ::: "memory");
    __syncthreads();
  }
#undef STAGE_A7

  int b = bh >> 4, hh = bh & 15;
#pragma unroll
  for (int qs = 0; qs < 2; ++qs)
#pragma unroll
    for (int j = 0; j < 4; ++j) {
      float rs = lwp[qs][j];
#pragma unroll
      for (int m = 8; m > 0; m >>= 1) rs += __shfl_xor(rs, m, 64);
      float inv = rs > 0.f ? 1.f / rs : 0.f;
      int row = b * 2048 + qlo + qs * 16 + lg * 4 + j;
#pragma unroll
      for (int dt = 0; dt < 4; ++dt)
        attb[(size_t)row * 1024 + hh * 64 + dt * 16 + ln15] = f2bf(oacc[qs][dt][j] * inv);
    }
}

extern "C" void kernel_launch(void* const* d_in, const int* in_sizes, int n_in,
                              void* d_out, int out_size, void* d_ws, size_t ws_size,
                              hipStream_t stream) {
  const float* x = (const float*)d_in[0];
  const float* Wqkv = (const float*)d_in[1];
  const float* bqkv = (const float*)d_in[2];
  const float* qg = (const float*)d_in[3];
  const float* qb = (const float*)d_in[4];
  const float* kg = (const float*)d_in[5];
  const float* kb = (const float*)d_in[6];
  const float* Wout = (const float*)d_in[7];
  const float* bout = (const float*)d_in[8];
  float* out = (float*)d_out;

  char* ws = (char*)d_ws;
  u16* attb = (u16*)(ws);                    // 8,388,608
  u16* Vt = (u16*)(ws + 8388608);            // 8,388,608
  u16* Qn = (u16*)(ws + 16777216);           // 8,388,608
  u16* Kn = (u16*)(ws + 25165824);           // 8,388,608
  u16* xb = (u16*)(ws + 33554432);           // 8,388,608
  u16* wqkvT = (u16*)(ws + 41943040);        // 6,291,456
  u16* woutT = (u16*)(ws + 48234496);        // 2,097,152  (total 50,331,648)

  // 1. casts / transposes
  k_cast4<<<4096, 256, 0, stream>>>(x, xb, 4194304 / 4);
  k_tcast<<<dim3(48, 16), 256, 0, stream>>>(Wqkv, wqkvT, 1024, 3072);
  k_tcast<<<dim3(16, 16), 256, 0, stream>>>(Wout, woutT, 1024, 1024);
  // 2. fused QKV GEMM + bias + qk-LN + head-split + V-transpose
  k_gemmqkv<<<768, 256, 0, stream>>>(xb, wqkvT, bqkv, qg, qb, kg, kb, Qn, Kn, Vt);
  // 3. sliding-window attention -> (B,S,E) bf16  (128-row blocks)
  k_attn7<<<512, 256, 0, stream>>>(Qn, Kn, Vt, attb);
  // 4. output GEMM (+bias) -> fp32
  k_gemm4<0><<<256, 256, 0, stream>>>(attb, woutT, bout, out, 4096, 1024, 1024);
}